// Round 4
// baseline (977.850 us; speedup 1.0000x reference)
//
#include <hip/hip_runtime.h>
#include <hip/hip_bf16.h>

// ============================================================================
// Qtran fused kernel, MI355X/gfx950.  Round 9: R8 (775us) proved the kernel is
// TLP-starved: 2 blocks/CU (LDS 61.4KB), ~70% idle, VALU/MFMA both low.
// This round halves LDS to 39.4KB -> 4 blocks/CU (Occ 23->~46%):
//  (1) phase A in-place single buffer (read full row to regs -> bar -> write),
//      stride 66 -> conflict-free b64 LDS ops; f0+f1 34.8KB -> 16.9KB.
//  (2) q_jt staging single-ctx (11KB), reused ctx0->ctx1 wave-locally.
//  (3) one-hot rows read from global (L1-resident 5.4KB table) not LDS.
// Numerics bit-identical to R8 (same fma order; one-hot now f32 = tighter).
// ============================================================================

#define B_TOT 262144

typedef __bf16 bf16_t;
typedef __bf16 bf16x4 __attribute__((ext_vector_type(4)));
typedef __bf16 bf16x8 __attribute__((ext_vector_type(8)));
typedef float  f32x2  __attribute__((ext_vector_type(2)));
typedef float  f32x4  __attribute__((ext_vector_type(4)));

#define MFMA16(a, b, c) __builtin_amdgcn_mfma_f32_16x16x32_bf16((a), (b), (c), 0, 0, 0)

// fragment-packed weight offsets in ws (bf16 elements). Layout per matrix:
// (((kc*NT)+nt)*64 + lane)*8 + j  holds
//   W[kc*32 + 16*(j>>2) + 4*(lane>>4) + (j&3)][nt*16 + (lane&15)]
// i.e. W^T as MFMA A-operand with sigma-permuted k (matches D->B chaining).
enum : int {
  OFF_VW1  = 0,
  OFF_L2W1 = 4096,
  OFF_L2W2 = 8192,
  OFF_L2W3 = 12288,
  OFF_L3W  = 16384,
  OFF_L4W  = 20480,
  OFF_QP1  = 22528,
  OFF_QP2  = 30720,
  OFF_QP3  = 38912,
  WS_ELEMS = 43008
};
#define WS_BYTES (WS_ELEMS * 2)

// output element offsets (fp32 elements, concatenated tuple)
enum : int {
  O_Q1   = 0,
  O_Q2   = 21 * B_TOT,
  O_JQ   = 42 * B_TOT,
  O_JMQ  = 43 * B_TOT,
  O_VT   = 44 * B_TOT,
  O_QJT  = 45 * B_TOT,
  O_QJTM = 87 * B_TOT
};

struct RDesc { const float* src; int K; int N; int NT; int off; };
struct RPack { RDesc d[9]; };

__global__ void repack_kernel(RPack P, bf16_t* __restrict__ ws) {
  RDesc d = P.d[blockIdx.x];
  int n = (d.K >> 5) * d.NT * 512;
  for (int i = threadIdx.x; i < n; i += blockDim.x) {
    int j  = i & 7;
    int l  = (i >> 3) & 63;
    int t  = i >> 9;          // kc*NT + nt
    int nt = t % d.NT;
    int kc = t / d.NT;
    int sk = kc * 32 + 16 * (j >> 2) + 4 * (l >> 4) + (j & 3);  // sigma-permuted k
    int sn = nt * 16 + (l & 15);
    float v = (sn < d.N) ? d.src[sk * d.N + sn] : 0.0f;
    ws[d.off + i] = (bf16_t)v;
  }
}

struct Args {
  const float* x; const int* a1; const int* a2;
  const float* ew1; const float* eb1; const float* ew2; const float* eb2;
  const float* qw1; const float* qb1; const float* qw2; const float* qb2;
  const float* vw1; const float* vb1; const float* vw2; const float* vb2;
  const float* l2w1; const float* l2b1; const float* l2w2; const float* l2b2;
  const float* l2w3; const float* l2b3;
  const float* l3w;  const float* l3b;  const float* l4w;  const float* l4b;
  const float* qpw1; const float* qpb1; const float* qpw2; const float* qpb2;
  const float* qpw3; const float* qpb3; const float* qpw4; const float* qpb4;
  float* out; const bf16_t* ws;
};

struct __align__(16) SMem {
  unsigned char scr[16896];   // phase A: f0 (f32, 64 rows x stride 66)
                              // phase B: q_jt staging float[64][43] (11008 B)
  bf16_t h1b[64 * 68];        // bf16 h1 (stride 68: 2-way bank alias = free)
  bf16_t h2b[64 * 68];
  float  bias[768];           // 0 v_b1 |64 l2_b1 |128 l2_b2 |192 l2_b3 |256 qp_b1(128)
                              // |384 qp_b2 |448 qp_b3 |512 l3_b |576 l4_b(pad32)
                              // |608 v_w2 |672 qp_w4 |736 v_b2 |737 qp_b4
  int    acts[128];           // b_act1[64] | b_act2[64]
  int    amax[128];           // argmax(q1)[64] | argmax(q2)[64]
  float  red[64][2];
  int    redi[64][2];
};                            // total 39424 B -> 4 blocks/CU

__device__ __forceinline__ float eluf(float x) { return x > 0.f ? x : expm1f(x); }

// fp32 64->64 layer, IN-PLACE on f (stride 66): read full row to regs (two
// 16-pair halves to cap liveness), compute packed f32x2, barrier, write back.
__device__ __forceinline__ void fcA64ip(float* __restrict__ f,
                                        const float* __restrict__ W,
                                        const float* __restrict__ Bv,
                                        bf16_t* __restrict__ hb, int r, int g) {
  f32x2 acc[8];
  const f32x2* Bv2 = (const f32x2*)(Bv + g * 16);
#pragma unroll
  for (int i = 0; i < 8; i++) acc[i] = Bv2[i];
  const f32x2* fr = (const f32x2*)(f + r * 66);
#pragma unroll 1
  for (int hh = 0; hh < 2; hh++) {
    f32x2 in[16];
#pragma unroll
    for (int i = 0; i < 16; i++) in[i] = fr[16 * hh + i];
#pragma unroll 4
    for (int k2 = 0; k2 < 16; k2++) {
      int k = 32 * hh + 2 * k2;
      const f32x2* wr0 = (const f32x2*)(W + k * 64 + g * 16);        // wave-uniform
      const f32x2* wr1 = (const f32x2*)(W + (k + 1) * 64 + g * 16);  // wave-uniform
      f32x2 a0 = {in[k2][0], in[k2][0]};
      f32x2 a1 = {in[k2][1], in[k2][1]};
#pragma unroll
      for (int i = 0; i < 8; i++) acc[i] += a0 * wr0[i];  // v_pk_fma_f32
#pragma unroll
      for (int i = 0; i < 8; i++) acc[i] += a1 * wr1[i];
    }
  }
  __syncthreads();  // all reads done before any in-place write
#pragma unroll
  for (int i = 0; i < 8; i++) {
    float v0 = fmaxf(acc[i][0], 0.f), v1 = fmaxf(acc[i][1], 0.f);
    f32x2 v = {v0, v1};
    *(f32x2*)(f + r * 66 + g * 16 + 2 * i) = v;
    if (hb) {
      hb[r * 68 + g * 16 + 2 * i]     = (bf16_t)v0;
      hb[r * 68 + g * 16 + 2 * i + 1] = (bf16_t)v1;
    }
  }
  __syncthreads();
}

// fp32 64->NC final q layer + fp32 store + in-thread argmax (strict >, ascending)
template <int NC>
__device__ __forceinline__ void qn2(const float* __restrict__ fin, const float* __restrict__ W21,
                                    const float* __restrict__ Bv, float* __restrict__ qo,
                                    int r, int colbase, float& bv, int& bi) {
  float acc[NC];
#pragma unroll
  for (int i = 0; i < NC; i++) acc[i] = Bv[colbase + i];
  for (int k2 = 0; k2 < 32; k2++) {
    f32x2 a = *(const f32x2*)(fin + r * 66 + 2 * k2);
    const float* wr0 = W21 + (2 * k2) * 21 + colbase;      // wave-uniform
    const float* wr1 = W21 + (2 * k2 + 1) * 21 + colbase;  // wave-uniform
#pragma unroll
    for (int i = 0; i < NC; i++) acc[i] = fmaf(a[0], wr0[i], acc[i]);
#pragma unroll
    for (int i = 0; i < NC; i++) acc[i] = fmaf(a[1], wr1[i], acc[i]);
  }
  bv = -3e38f; bi = 0;
#pragma unroll
  for (int i = 0; i < NC; i++) {
    qo[i] = acc[i];
    if (acc[i] > bv) { bv = acc[i]; bi = colbase + i; }
  }
}

// One transposed D-tile: bias + sum_kc Atilde(woff,kc,nt) x bin[kc].
// Output tile nt covers features n2 = nt*16 + 4u + p for batch row c.
template <bool USEWS, int NT, int KC>
__device__ __forceinline__ f32x4 tileT(const bf16x8* __restrict__ WF,
                                       const float* __restrict__ Wp, int N, int woff,
                                       const bf16x8* __restrict__ bin,
                                       const float* __restrict__ bias, int bbase,
                                       int nt, int l, int c, int u) {
  f32x4 a = *(const f32x4*)(bias + bbase + nt * 16 + 4 * u);
#pragma unroll
  for (int kc = 0; kc < KC; kc++) {
    bf16x8 w;
    if constexpr (USEWS) {
      w = WF[(woff >> 3) + (kc * NT + nt) * 64 + l];
    } else {
      int sn = nt * 16 + c;
      if (sn < N) {
#pragma unroll
        for (int j = 0; j < 8; j++)
          w[j] = (bf16_t)Wp[(kc * 32 + 16 * (j >> 2) + 4 * u + (j & 3)) * N + sn];
      } else {
#pragma unroll
        for (int j = 0; j < 8; j++) w[j] = (bf16_t)0.0f;
      }
    }
    a = MFMA16(w, bin[kc], a);
  }
  return a;
}

// Two D-tiles -> one next-layer B-fragment.  MODE: 0=identity, 1=relu, 2=elu.
// r[j] = act( (j>>2 ? t1 : t0)[j&3] )   (the sigma chaining identity)
template <int MODE>
__device__ __forceinline__ bf16x8 pack2(f32x4 t0, f32x4 t1) {
  bf16x8 r;
#pragma unroll
  for (int j = 0; j < 8; j++) {
    float v = (j >> 2) ? t1[j & 3] : t0[j & 3];
    if constexpr (MODE == 1) v = fmaxf(v, 0.f);
    if constexpr (MODE == 2) v = eluf(v);
    r[j] = (bf16_t)v;
  }
  return r;
}

template <bool USEWS>
__global__ __launch_bounds__(256, 4) void qtran_main(Args A) {
  __shared__ SMem sm;
  const int t = threadIdx.x;
  const int wgbase = blockIdx.x * 64;
  const int r = t & 63;
  const int g = __builtin_amdgcn_readfirstlane(t >> 6);

  float* f0 = (float*)sm.scr;  // stride 66

  // ---- stage small tables ----
  if (t < 64) {
    sm.bias[t]        = A.vb1[t];
    sm.bias[64 + t]   = A.l2b1[t];
    sm.bias[128 + t]  = A.l2b2[t];
    sm.bias[192 + t]  = A.l2b3[t];
    sm.bias[384 + t]  = A.qpb2[t];
    sm.bias[448 + t]  = A.qpb3[t];
    sm.bias[512 + t]  = A.l3b[t];
    sm.bias[608 + t]  = A.vw2[t];
    sm.bias[672 + t]  = A.qpw4[t];
    sm.acts[t]        = A.a1[wgbase + t];
    sm.acts[64 + t]   = A.a2[wgbase + t];
  } else if (t < 192) {
    sm.bias[256 + t - 64] = A.qpb1[t - 64];
  } else if (t < 224) {
    int i = t - 192;
    sm.bias[576 + i] = (i < 21) ? A.l4b[i] : 0.0f;
  } else if (t == 224) {
    sm.bias[736] = A.vb2[0];
    sm.bias[737] = A.qpb4[0];
  }

  // =========================== phase A (fp32, in-place) ===========================
  const int rowg = wgbase + r;
  float4 xv = ((const float4*)A.x)[rowg];
#pragma unroll 1
  for (int s = 0; s < 2; ++s) {
    float xa = s ? xv.z : xv.x;
    float xb = s ? xv.w : xv.y;
#pragma unroll
    for (int cc = 0; cc < 16; cc += 2) {
      int col = g * 16 + cc;
      float h0 = fmaf(xa, A.ew1[col],     fmaf(xb, A.ew1[64 + col],     A.eb1[col]));
      float h1 = fmaf(xa, A.ew1[col + 1], fmaf(xb, A.ew1[64 + col + 1], A.eb1[col + 1]));
      f32x2 v = {fmaxf(h0, 0.f), fmaxf(h1, 0.f)};
      *(f32x2*)(f0 + r * 66 + col) = v;
    }
    __syncthreads();
    fcA64ip(f0, A.ew2, A.eb2, s ? sm.h2b : sm.h1b, r, g);
    fcA64ip(f0, A.qw1, A.qb1, nullptr, r, g);
    {
      float* qo = A.out + (s ? O_Q2 : O_Q1) + rowg * 21;
      float bv; int bi;
      if (g == 0) {
        qn2<16>(f0, A.qw2, A.qb2, qo, r, 0, bv, bi);
        sm.red[r][0] = bv; sm.redi[r][0] = bi;
      } else if (g == 1) {
        qn2<5>(f0, A.qw2, A.qb2, qo + 16, r, 16, bv, bi);
        sm.red[r][1] = bv; sm.redi[r][1] = bi;
      }
    }
    __syncthreads();
    if (t < 64)  // >= prefers lower column block => first-max semantics
      sm.amax[s * 64 + t] = (sm.red[t][0] >= sm.red[t][1]) ? sm.redi[t][0] : sm.redi[t][1];
    __syncthreads();
  }

  // ====== phase B (transposed, register-resident, dual-context, barrier-free) ======
  const int l = t & 63;
  const int c = l & 15, u = l >> 4;     // c = batch-row-in-wave (D col), u = lane-high
  const int rb = g * 16;                // this wave's row base (uniform)
  const int row = rb + c;               // this lane's batch row
  float* out = A.out;
  const bf16x8* WF = (const bf16x8*)A.ws;
  const float* bias = sm.bias;
  float* S = (float*)sm.scr;            // q_jt staging: float[64][43], reused per ctx

  // sigma-layout gather of h^T from LDS: frag[j] = h[row][kc*32+16*(j>>2)+4u+(j&3)]
  auto HG = [&](const bf16_t* __restrict__ HB, int kc) -> bf16x8 {
    const bf16_t* p = HB + row * 68 + kc * 32 + 4 * u;
    bf16x4 lo = *(const bf16x4*)p;
    bf16x4 hi = *(const bf16x4*)(p + 16);
    bf16x8 rr;
#pragma unroll
    for (int d = 0; d < 4; d++) { rr[d] = lo[d]; rr[4 + d] = hi[d]; }
    return rr;
  };

  // ---- vtot = relu((h1+h2)@v_w1 + v_b1) @ v_w2 + v_b2 ----
  {
    bf16x8 aS[2];
#pragma unroll
    for (int kc = 0; kc < 2; kc++) {
      bf16x8 a1 = HG(sm.h1b, kc), a2 = HG(sm.h2b, kc);
      bf16x8 s8;
#pragma unroll
      for (int i = 0; i < 8; i++) s8[i] = (bf16_t)((float)a1[i] + (float)a2[i]);
      aS[kc] = s8;
    }
    float pr = 0.f;
#pragma unroll
    for (int nt = 0; nt < 4; nt++) {
      f32x4 tv = tileT<USEWS, 4, 2>(WF, A.vw1, 64, OFF_VW1, aS, bias, 0, nt, l, c, u);
      f32x4 wv = *(const f32x4*)(bias + 608 + nt * 16 + 4 * u);
#pragma unroll
      for (int p = 0; p < 4; p++) pr += fmaxf(tv[p], 0.f) * wv[p];
    }
    pr += __shfl_xor(pr, 16, 64);
    pr += __shfl_xor(pr, 32, 64);
    if (u == 0) out[O_VT + wgbase + row] = pr + bias[736];
  }

  // ---- fused dual-context joint(): ctx0 = (b_act1,b_act2), ctx1 = (argmax) ----
  const int* actsrc[2] = {sm.acts, sm.amax};
  bf16x8 k1f[2][2][2];   // [ctx][j][kc] key1_j sigma B-fragments
  f32x4 msum[2][4];      // [ctx] f32 sum over j of key1 tiles

#pragma unroll
  for (int j = 0; j < 2; j++) {
    const bf16_t* HB = j ? sm.h2b : sm.h1b;
    bf16x8 bh[2];
#pragma unroll
    for (int kc = 0; kc < 2; kc++) bh[kc] = HG(HB, kc);
    // lin2-L1 MFMA part depends only on h -> computed ONCE, shared by both ctx
    f32x4 tS[4];
#pragma unroll
    for (int nt = 0; nt < 4; nt++)
      tS[nt] = tileT<USEWS, 4, 2>(WF, A.l2w1, 64, OFF_L2W1, bh, bias, 64, nt, l, c, u);
    // per-ctx one-hot add (f32 from global; 5.4KB table is L1-resident) + relu pack
    bf16x8 b1[2][2];
#pragma unroll
    for (int x = 0; x < 2; x++) {
      const int act = actsrc[x][j * 64 + row];
      const float* ohp = A.l2w1 + (64 + act) * 64 + 4 * u;
      f32x4 tt0 = tS[0] + *(const f32x4*)(ohp);
      f32x4 tt1 = tS[1] + *(const f32x4*)(ohp + 16);
      f32x4 tt2 = tS[2] + *(const f32x4*)(ohp + 32);
      f32x4 tt3 = tS[3] + *(const f32x4*)(ohp + 48);
      b1[x][0] = pack2<1>(tt0, tt1);
      b1[x][1] = pack2<1>(tt2, tt3);
    }
    // lin2-L2 (both ctx interleaved)
    bf16x8 b2[2][2];
#pragma unroll
    for (int x = 0; x < 2; x++)
#pragma unroll
      for (int f = 0; f < 2; f++) {
        f32x4 t0 = tileT<USEWS, 4, 2>(WF, A.l2w2, 64, OFF_L2W2, b1[x], bias, 128, 2 * f, l, c, u);
        f32x4 t1 = tileT<USEWS, 4, 2>(WF, A.l2w2, 64, OFF_L2W2, b1[x], bias, 128, 2 * f + 1, l, c, u);
        b2[x][f] = pack2<1>(t0, t1);
      }
    // lin2-L3 (both ctx interleaved) -> key1_j fragments + f32 tiles for the mean
#pragma unroll
    for (int x = 0; x < 2; x++)
#pragma unroll
      for (int f = 0; f < 2; f++) {
        f32x4 t0 = tileT<USEWS, 4, 2>(WF, A.l2w3, 64, OFF_L2W3, b2[x], bias, 192, 2 * f, l, c, u);
        f32x4 t1 = tileT<USEWS, 4, 2>(WF, A.l2w3, 64, OFF_L2W3, b2[x], bias, 192, 2 * f + 1, l, c, u);
        k1f[x][j][f] = pack2<0>(t0, t1);
        if (j == 0) { msum[x][2 * f] = t0; msum[x][2 * f + 1] = t1; }
        else        { msum[x][2 * f] += t0; msum[x][2 * f + 1] += t1; }
      }
  }

  // ---- q_jt per ctx: compute -> stage in S -> wave-local coalesced writeback ----
#pragma unroll
  for (int x = 0; x < 2; x++) {
#pragma unroll
    for (int j = 0; j < 2; j++) {
      const bf16_t* HB = j ? sm.h2b : sm.h1b;
      bf16x8 aZ[2];
#pragma unroll
      for (int kc = 0; kc < 2; kc++) {
        bf16x8 h8 = HG(HB, kc);
        bf16x8 kk = k1f[x][1 - j][kc];
#pragma unroll
        for (int i = 0; i < 8; i++)
          aZ[kc][i] = (bf16_t)((float)h8[i] + 0.5f * (float)kk[i]);
      }
      bf16x8 bz[2];
#pragma unroll
      for (int f = 0; f < 2; f++) {
        f32x4 t0 = tileT<USEWS, 4, 2>(WF, A.l3w, 64, OFF_L3W, aZ, bias, 512, 2 * f, l, c, u);
        f32x4 t1 = tileT<USEWS, 4, 2>(WF, A.l3w, 64, OFF_L3W, aZ, bias, 512, 2 * f + 1, l, c, u);
        bz[f] = pack2<1>(t0, t1);
      }
#pragma unroll
      for (int nt = 0; nt < 2; nt++) {
        f32x4 tq = tileT<USEWS, 2, 2>(WF, A.l4w, 21, OFF_L4W, bz, bias, 576, nt, l, c, u);
#pragma unroll
        for (int p = 0; p < 4; p++) {
          int n2 = nt * 16 + 4 * u + p;
          if (n2 < 21) S[row * 43 + j * 21 + n2] = tq[p];
        }
      }
    }
    // wave-local writeback (own 16 rows; same-wave DS ordering => no barrier)
    const int ob = (x ? O_QJTM : O_QJT) + (wgbase + rb) * 42;
    const float* Sx = S + rb * 43;
    for (int i2 = l; i2 < 672; i2 += 64)
      out[ob + i2] = Sx[(i2 / 42) * 43 + (i2 % 42)];
  }

  // ---- q_prime chain (both ctx interleaved) ----
  {
    bf16x8 aM[2][2];
#pragma unroll
    for (int x = 0; x < 2; x++)
#pragma unroll
      for (int kc = 0; kc < 2; kc++) {
        f32x4 m0 = 0.5f * msum[x][2 * kc], m1 = 0.5f * msum[x][2 * kc + 1];
        aM[x][kc] = pack2<0>(m0, m1);
      }
    bf16x8 bq[2][4];
#pragma unroll
    for (int x = 0; x < 2; x++)
#pragma unroll
      for (int f = 0; f < 4; f++) {
        f32x4 t0 = tileT<USEWS, 8, 2>(WF, A.qpw1, 128, OFF_QP1, aM[x], bias, 256, 2 * f, l, c, u);
        f32x4 t1 = tileT<USEWS, 8, 2>(WF, A.qpw1, 128, OFF_QP1, aM[x], bias, 256, 2 * f + 1, l, c, u);
        bq[x][f] = pack2<2>(t0, t1);
      }
    bf16x8 b3[2][2];
#pragma unroll
    for (int x = 0; x < 2; x++)
#pragma unroll
      for (int f = 0; f < 2; f++) {
        f32x4 t0 = tileT<USEWS, 4, 4>(WF, A.qpw2, 64, OFF_QP2, bq[x], bias, 384, 2 * f, l, c, u);
        f32x4 t1 = tileT<USEWS, 4, 4>(WF, A.qpw2, 64, OFF_QP2, bq[x], bias, 384, 2 * f + 1, l, c, u);
        b3[x][f] = pack2<2>(t0, t1);
      }
    float pj[2] = {0.f, 0.f};
#pragma unroll
    for (int x = 0; x < 2; x++)
#pragma unroll
      for (int nt = 0; nt < 4; nt++) {
        f32x4 tq = tileT<USEWS, 4, 2>(WF, A.qpw3, 64, OFF_QP3, b3[x], bias, 448, nt, l, c, u);
        f32x4 w4 = *(const f32x4*)(bias + 672 + nt * 16 + 4 * u);
#pragma unroll
        for (int p = 0; p < 4; p++) pj[x] += eluf(tq[p]) * w4[p];
      }
#pragma unroll
    for (int x = 0; x < 2; x++) {
      float v = pj[x];
      v += __shfl_xor(v, 16, 64);
      v += __shfl_xor(v, 32, 64);
      if (u == 0) out[(x ? O_JMQ : O_JQ) + wgbase + row] = v + bias[737];
    }
  }
}

extern "C" void kernel_launch(void* const* d_in, const int* in_sizes, int n_in,
                              void* d_out, int out_size, void* d_ws, size_t ws_size,
                              hipStream_t stream) {
  (void)in_sizes; (void)n_in; (void)out_size;
  Args A;
  A.x    = (const float*)d_in[0];
  A.a1   = (const int*)d_in[1];
  A.a2   = (const int*)d_in[2];
  A.ew1  = (const float*)d_in[3];
  A.eb1  = (const float*)d_in[4];
  A.ew2  = (const float*)d_in[5];
  A.eb2  = (const float*)d_in[6];
  A.qw1  = (const float*)d_in[7];
  A.qb1  = (const float*)d_in[8];
  A.qw2  = (const float*)d_in[9];
  A.qb2  = (const float*)d_in[10];
  A.vw1  = (const float*)d_in[11];
  A.vb1  = (const float*)d_in[12];
  A.vw2  = (const float*)d_in[13];
  A.vb2  = (const float*)d_in[14];
  A.l2w1 = (const float*)d_in[15];
  A.l2b1 = (const float*)d_in[16];
  A.l2w2 = (const float*)d_in[17];
  A.l2b2 = (const float*)d_in[18];
  A.l2w3 = (const float*)d_in[19];
  A.l2b3 = (const float*)d_in[20];
  A.l3w  = (const float*)d_in[21];
  A.l3b  = (const float*)d_in[22];
  A.l4w  = (const float*)d_in[23];
  A.l4b  = (const float*)d_in[24];
  A.qpw1 = (const float*)d_in[25];
  A.qpb1 = (const float*)d_in[26];
  A.qpw2 = (const float*)d_in[27];
  A.qpb2 = (const float*)d_in[28];
  A.qpw3 = (const float*)d_in[29];
  A.qpb3 = (const float*)d_in[30];
  A.qpw4 = (const float*)d_in[31];
  A.qpb4 = (const float*)d_in[32];
  A.out  = (float*)d_out;
  A.ws   = (const bf16_t*)d_ws;

  if (ws_size >= (size_t)WS_BYTES) {
    bf16_t* ws = (bf16_t*)d_ws;
    RPack P;
    P.d[0] = {A.vw1,  64, 64,  4, OFF_VW1};
    P.d[1] = {A.l2w1, 64, 64,  4, OFF_L2W1};   // rows 0..63 (one-hot rows from global)
    P.d[2] = {A.l2w2, 64, 64,  4, OFF_L2W2};
    P.d[3] = {A.l2w3, 64, 64,  4, OFF_L2W3};
    P.d[4] = {A.l3w,  64, 64,  4, OFF_L3W};
    P.d[5] = {A.l4w,  64, 21,  2, OFF_L4W};    // N padded 21 -> 32 with zeros
    P.d[6] = {A.qpw1, 64, 128, 8, OFF_QP1};
    P.d[7] = {A.qpw2, 128, 64, 4, OFF_QP2};
    P.d[8] = {A.qpw3, 64, 64,  4, OFF_QP3};
    hipLaunchKernelGGL(repack_kernel, dim3(9), dim3(256), 0, stream, P, ws);
    hipLaunchKernelGGL(HIP_KERNEL_NAME(qtran_main<true>), dim3(B_TOT / 64), dim3(256), 0,
                       stream, A);
  } else {
    hipLaunchKernelGGL(HIP_KERNEL_NAME(qtran_main<false>), dim3(B_TOT / 64), dim3(256), 0,
                       stream, A);
  }
}

// Round 5
// 895.102 us; speedup vs baseline: 1.0924x; 1.0924x over previous
//
#include <hip/hip_runtime.h>
#include <hip/hip_bf16.h>

// ============================================================================
// Qtran fused kernel, MI355X/gfx950.  Round 10: R9 doubled occupancy (45%) via
// the 39.4KB LDS diet but __launch_bounds__(256,4) capped regs at 128 total ->
// allocator split 64 arch + AGPR and SPILLED phase B (FETCH 4->165MB, WRITE
// 132->517MB), dur 775->849.  Fix: keep the LDS diet, drop the forced cap
// (launch_bounds(256,2)), and cut phase-B liveness so the natural allocation
// fits 128 and HW gives 4 blocks/CU on its own:
//   - single-context J (called twice): k1f/msum liveness halved vs dual-ctx
//   - msum -> aM converted immediately after the j-loop (frees 16 regs)
//   - q_jt before qp chain (k1f dies early)  [kept from R8/R9]
// Phase A in-place single-buffer + one-hot-from-global kept from R9.
// ============================================================================

#define B_TOT 262144

typedef __bf16 bf16_t;
typedef __bf16 bf16x4 __attribute__((ext_vector_type(4)));
typedef __bf16 bf16x8 __attribute__((ext_vector_type(8)));
typedef float  f32x2  __attribute__((ext_vector_type(2)));
typedef float  f32x4  __attribute__((ext_vector_type(4)));

#define MFMA16(a, b, c) __builtin_amdgcn_mfma_f32_16x16x32_bf16((a), (b), (c), 0, 0, 0)

// fragment-packed weight offsets in ws (bf16 elements). Layout per matrix:
// (((kc*NT)+nt)*64 + lane)*8 + j  holds
//   W[kc*32 + 16*(j>>2) + 4*(lane>>4) + (j&3)][nt*16 + (lane&15)]
// i.e. W^T as MFMA A-operand with sigma-permuted k (matches D->B chaining).
enum : int {
  OFF_VW1  = 0,
  OFF_L2W1 = 4096,
  OFF_L2W2 = 8192,
  OFF_L2W3 = 12288,
  OFF_L3W  = 16384,
  OFF_L4W  = 20480,
  OFF_QP1  = 22528,
  OFF_QP2  = 30720,
  OFF_QP3  = 38912,
  WS_ELEMS = 43008
};
#define WS_BYTES (WS_ELEMS * 2)

// output element offsets (fp32 elements, concatenated tuple)
enum : int {
  O_Q1   = 0,
  O_Q2   = 21 * B_TOT,
  O_JQ   = 42 * B_TOT,
  O_JMQ  = 43 * B_TOT,
  O_VT   = 44 * B_TOT,
  O_QJT  = 45 * B_TOT,
  O_QJTM = 87 * B_TOT
};

struct RDesc { const float* src; int K; int N; int NT; int off; };
struct RPack { RDesc d[9]; };

__global__ void repack_kernel(RPack P, bf16_t* __restrict__ ws) {
  RDesc d = P.d[blockIdx.x];
  int n = (d.K >> 5) * d.NT * 512;
  for (int i = threadIdx.x; i < n; i += blockDim.x) {
    int j  = i & 7;
    int l  = (i >> 3) & 63;
    int t  = i >> 9;          // kc*NT + nt
    int nt = t % d.NT;
    int kc = t / d.NT;
    int sk = kc * 32 + 16 * (j >> 2) + 4 * (l >> 4) + (j & 3);  // sigma-permuted k
    int sn = nt * 16 + (l & 15);
    float v = (sn < d.N) ? d.src[sk * d.N + sn] : 0.0f;
    ws[d.off + i] = (bf16_t)v;
  }
}

struct Args {
  const float* x; const int* a1; const int* a2;
  const float* ew1; const float* eb1; const float* ew2; const float* eb2;
  const float* qw1; const float* qb1; const float* qw2; const float* qb2;
  const float* vw1; const float* vb1; const float* vw2; const float* vb2;
  const float* l2w1; const float* l2b1; const float* l2w2; const float* l2b2;
  const float* l2w3; const float* l2b3;
  const float* l3w;  const float* l3b;  const float* l4w;  const float* l4b;
  const float* qpw1; const float* qpb1; const float* qpw2; const float* qpb2;
  const float* qpw3; const float* qpb3; const float* qpw4; const float* qpb4;
  float* out; const bf16_t* ws;
};

struct __align__(16) SMem {
  unsigned char scr[16896];   // phase A: f0 (f32, 64 rows x stride 66)
                              // phase B: q_jt staging float[64][43] (11008 B)
  bf16_t h1b[64 * 68];        // bf16 h1 (stride 68: 2-way bank alias = free)
  bf16_t h2b[64 * 68];
  float  bias[768];           // 0 v_b1 |64 l2_b1 |128 l2_b2 |192 l2_b3 |256 qp_b1(128)
                              // |384 qp_b2 |448 qp_b3 |512 l3_b |576 l4_b(pad32)
                              // |608 v_w2 |672 qp_w4 |736 v_b2 |737 qp_b4
  int    acts[128];           // b_act1[64] | b_act2[64]
  int    amax[128];           // argmax(q1)[64] | argmax(q2)[64]
  float  red[64][2];
  int    redi[64][2];
};                            // total 39424 B -> 4 blocks/CU (if VGPR <= 128)

__device__ __forceinline__ float eluf(float x) { return x > 0.f ? x : expm1f(x); }

// fp32 64->64 layer, IN-PLACE on f (stride 66): read full row to regs (two
// 16-pair halves to cap liveness), compute packed f32x2, barrier, write back.
__device__ __forceinline__ void fcA64ip(float* __restrict__ f,
                                        const float* __restrict__ W,
                                        const float* __restrict__ Bv,
                                        bf16_t* __restrict__ hb, int r, int g) {
  f32x2 acc[8];
  const f32x2* Bv2 = (const f32x2*)(Bv + g * 16);
#pragma unroll
  for (int i = 0; i < 8; i++) acc[i] = Bv2[i];
  const f32x2* fr = (const f32x2*)(f + r * 66);
#pragma unroll 1
  for (int hh = 0; hh < 2; hh++) {
    f32x2 in[16];
#pragma unroll
    for (int i = 0; i < 16; i++) in[i] = fr[16 * hh + i];
#pragma unroll 4
    for (int k2 = 0; k2 < 16; k2++) {
      int k = 32 * hh + 2 * k2;
      const f32x2* wr0 = (const f32x2*)(W + k * 64 + g * 16);        // wave-uniform
      const f32x2* wr1 = (const f32x2*)(W + (k + 1) * 64 + g * 16);  // wave-uniform
      f32x2 a0 = {in[k2][0], in[k2][0]};
      f32x2 a1 = {in[k2][1], in[k2][1]};
#pragma unroll
      for (int i = 0; i < 8; i++) acc[i] += a0 * wr0[i];  // v_pk_fma_f32
#pragma unroll
      for (int i = 0; i < 8; i++) acc[i] += a1 * wr1[i];
    }
  }
  __syncthreads();  // all reads done before any in-place write
#pragma unroll
  for (int i = 0; i < 8; i++) {
    float v0 = fmaxf(acc[i][0], 0.f), v1 = fmaxf(acc[i][1], 0.f);
    f32x2 v = {v0, v1};
    *(f32x2*)(f + r * 66 + g * 16 + 2 * i) = v;
    if (hb) {
      hb[r * 68 + g * 16 + 2 * i]     = (bf16_t)v0;
      hb[r * 68 + g * 16 + 2 * i + 1] = (bf16_t)v1;
    }
  }
  __syncthreads();
}

// fp32 64->NC final q layer + fp32 store + in-thread argmax (strict >, ascending)
template <int NC>
__device__ __forceinline__ void qn2(const float* __restrict__ fin, const float* __restrict__ W21,
                                    const float* __restrict__ Bv, float* __restrict__ qo,
                                    int r, int colbase, float& bv, int& bi) {
  float acc[NC];
#pragma unroll
  for (int i = 0; i < NC; i++) acc[i] = Bv[colbase + i];
  for (int k2 = 0; k2 < 32; k2++) {
    f32x2 a = *(const f32x2*)(fin + r * 66 + 2 * k2);
    const float* wr0 = W21 + (2 * k2) * 21 + colbase;      // wave-uniform
    const float* wr1 = W21 + (2 * k2 + 1) * 21 + colbase;  // wave-uniform
#pragma unroll
    for (int i = 0; i < NC; i++) acc[i] = fmaf(a[0], wr0[i], acc[i]);
#pragma unroll
    for (int i = 0; i < NC; i++) acc[i] = fmaf(a[1], wr1[i], acc[i]);
  }
  bv = -3e38f; bi = 0;
#pragma unroll
  for (int i = 0; i < NC; i++) {
    qo[i] = acc[i];
    if (acc[i] > bv) { bv = acc[i]; bi = colbase + i; }
  }
}

// One transposed D-tile: bias + sum_kc Atilde(woff,kc,nt) x bin[kc].
// Output tile nt covers features n2 = nt*16 + 4u + p for batch row c.
template <bool USEWS, int NT, int KC>
__device__ __forceinline__ f32x4 tileT(const bf16x8* __restrict__ WF,
                                       const float* __restrict__ Wp, int N, int woff,
                                       const bf16x8* __restrict__ bin,
                                       const float* __restrict__ bias, int bbase,
                                       int nt, int l, int c, int u) {
  f32x4 a = *(const f32x4*)(bias + bbase + nt * 16 + 4 * u);
#pragma unroll
  for (int kc = 0; kc < KC; kc++) {
    bf16x8 w;
    if constexpr (USEWS) {
      w = WF[(woff >> 3) + (kc * NT + nt) * 64 + l];
    } else {
      int sn = nt * 16 + c;
      if (sn < N) {
#pragma unroll
        for (int j = 0; j < 8; j++)
          w[j] = (bf16_t)Wp[(kc * 32 + 16 * (j >> 2) + 4 * u + (j & 3)) * N + sn];
      } else {
#pragma unroll
        for (int j = 0; j < 8; j++) w[j] = (bf16_t)0.0f;
      }
    }
    a = MFMA16(w, bin[kc], a);
  }
  return a;
}

// Two D-tiles -> one next-layer B-fragment.  MODE: 0=identity, 1=relu, 2=elu.
// r[j] = act( (j>>2 ? t1 : t0)[j&3] )   (the sigma chaining identity)
template <int MODE>
__device__ __forceinline__ bf16x8 pack2(f32x4 t0, f32x4 t1) {
  bf16x8 r;
#pragma unroll
  for (int j = 0; j < 8; j++) {
    float v = (j >> 2) ? t1[j & 3] : t0[j & 3];
    if constexpr (MODE == 1) v = fmaxf(v, 0.f);
    if constexpr (MODE == 2) v = eluf(v);
    r[j] = (bf16_t)v;
  }
  return r;
}

template <bool USEWS>
__global__ __launch_bounds__(256, 2) void qtran_main(Args A) {
  __shared__ SMem sm;
  const int t = threadIdx.x;
  const int wgbase = blockIdx.x * 64;
  const int r = t & 63;
  const int g = __builtin_amdgcn_readfirstlane(t >> 6);

  float* f0 = (float*)sm.scr;  // stride 66

  // ---- stage small tables ----
  if (t < 64) {
    sm.bias[t]        = A.vb1[t];
    sm.bias[64 + t]   = A.l2b1[t];
    sm.bias[128 + t]  = A.l2b2[t];
    sm.bias[192 + t]  = A.l2b3[t];
    sm.bias[384 + t]  = A.qpb2[t];
    sm.bias[448 + t]  = A.qpb3[t];
    sm.bias[512 + t]  = A.l3b[t];
    sm.bias[608 + t]  = A.vw2[t];
    sm.bias[672 + t]  = A.qpw4[t];
    sm.acts[t]        = A.a1[wgbase + t];
    sm.acts[64 + t]   = A.a2[wgbase + t];
  } else if (t < 192) {
    sm.bias[256 + t - 64] = A.qpb1[t - 64];
  } else if (t < 224) {
    int i = t - 192;
    sm.bias[576 + i] = (i < 21) ? A.l4b[i] : 0.0f;
  } else if (t == 224) {
    sm.bias[736] = A.vb2[0];
    sm.bias[737] = A.qpb4[0];
  }

  // =========================== phase A (fp32, in-place) ===========================
  const int rowg = wgbase + r;
  float4 xv = ((const float4*)A.x)[rowg];
#pragma unroll 1
  for (int s = 0; s < 2; ++s) {
    float xa = s ? xv.z : xv.x;
    float xb = s ? xv.w : xv.y;
#pragma unroll
    for (int cc = 0; cc < 16; cc += 2) {
      int col = g * 16 + cc;
      float h0 = fmaf(xa, A.ew1[col],     fmaf(xb, A.ew1[64 + col],     A.eb1[col]));
      float h1 = fmaf(xa, A.ew1[col + 1], fmaf(xb, A.ew1[64 + col + 1], A.eb1[col + 1]));
      f32x2 v = {fmaxf(h0, 0.f), fmaxf(h1, 0.f)};
      *(f32x2*)(f0 + r * 66 + col) = v;
    }
    __syncthreads();
    fcA64ip(f0, A.ew2, A.eb2, s ? sm.h2b : sm.h1b, r, g);
    fcA64ip(f0, A.qw1, A.qb1, nullptr, r, g);
    {
      float* qo = A.out + (s ? O_Q2 : O_Q1) + rowg * 21;
      float bv; int bi;
      if (g == 0) {
        qn2<16>(f0, A.qw2, A.qb2, qo, r, 0, bv, bi);
        sm.red[r][0] = bv; sm.redi[r][0] = bi;
      } else if (g == 1) {
        qn2<5>(f0, A.qw2, A.qb2, qo + 16, r, 16, bv, bi);
        sm.red[r][1] = bv; sm.redi[r][1] = bi;
      }
    }
    __syncthreads();
    if (t < 64)  // >= prefers lower column block => first-max semantics
      sm.amax[s * 64 + t] = (sm.red[t][0] >= sm.red[t][1]) ? sm.redi[t][0] : sm.redi[t][1];
    __syncthreads();
  }

  // ====== phase B (transposed, register-resident, single-ctx x2, barrier-free) ======
  const int l = t & 63;
  const int c = l & 15, u = l >> 4;     // c = batch-row-in-wave (D col), u = lane-high
  const int rb = g * 16;                // this wave's row base (uniform)
  const int row = rb + c;               // this lane's batch row
  float* out = A.out;
  const bf16x8* WF = (const bf16x8*)A.ws;
  const float* bias = sm.bias;
  float* S = (float*)sm.scr;            // q_jt staging: float[64][43], reused per ctx

  // sigma-layout gather of h^T from LDS: frag[j] = h[row][kc*32+16*(j>>2)+4u+(j&3)]
  auto HG = [&](const bf16_t* __restrict__ HB, int kc) -> bf16x8 {
    const bf16_t* p = HB + row * 68 + kc * 32 + 4 * u;
    bf16x4 lo = *(const bf16x4*)p;
    bf16x4 hi = *(const bf16x4*)(p + 16);
    bf16x8 rr;
#pragma unroll
    for (int d = 0; d < 4; d++) { rr[d] = lo[d]; rr[4 + d] = hi[d]; }
    return rr;
  };

  // ---- vtot = relu((h1+h2)@v_w1 + v_b1) @ v_w2 + v_b2 ----
  {
    bf16x8 aS[2];
#pragma unroll
    for (int kc = 0; kc < 2; kc++) {
      bf16x8 a1 = HG(sm.h1b, kc), a2 = HG(sm.h2b, kc);
      bf16x8 s8;
#pragma unroll
      for (int i = 0; i < 8; i++) s8[i] = (bf16_t)((float)a1[i] + (float)a2[i]);
      aS[kc] = s8;
    }
    float pr = 0.f;
#pragma unroll
    for (int nt = 0; nt < 4; nt++) {
      f32x4 tv = tileT<USEWS, 4, 2>(WF, A.vw1, 64, OFF_VW1, aS, bias, 0, nt, l, c, u);
      f32x4 wv = *(const f32x4*)(bias + 608 + nt * 16 + 4 * u);
#pragma unroll
      for (int p = 0; p < 4; p++) pr += fmaxf(tv[p], 0.f) * wv[p];
    }
    pr += __shfl_xor(pr, 16, 64);
    pr += __shfl_xor(pr, 32, 64);
    if (u == 0) out[O_VT + wgbase + row] = pr + bias[736];
  }

  // ---- single-context joint(); called for ctx0 (b_act) then ctx1 (argmax) ----
  auto J = [&](const int* __restrict__ asrc, int jointBase, int qjtBase) {
    bf16x8 k1f[2][2];   // [j][kc] key1_j sigma B-fragments
    f32x4 msum[4];      // f32 sum over j of key1 tiles
#pragma unroll
    for (int j = 0; j < 2; j++) {
      const bf16_t* HB = j ? sm.h2b : sm.h1b;
      const int act = asrc[j * 64 + row];
      bf16x8 bh[2];
#pragma unroll
      for (int kc = 0; kc < 2; kc++) bh[kc] = HG(HB, kc);
      // lin2-L1 + one-hot add (f32 from global; 5.4KB table L1-resident) + relu
      const float* ohp = A.l2w1 + (64 + act) * 64 + 4 * u;
      bf16x8 b1[2];
#pragma unroll
      for (int f = 0; f < 2; f++) {
        f32x4 t0 = tileT<USEWS, 4, 2>(WF, A.l2w1, 64, OFF_L2W1, bh, bias, 64, 2 * f, l, c, u);
        f32x4 t1 = tileT<USEWS, 4, 2>(WF, A.l2w1, 64, OFF_L2W1, bh, bias, 64, 2 * f + 1, l, c, u);
        t0 += *(const f32x4*)(ohp + (2 * f) * 16);
        t1 += *(const f32x4*)(ohp + (2 * f + 1) * 16);
        b1[f] = pack2<1>(t0, t1);
      }
      // lin2-L2, relu
      bf16x8 b2[2];
#pragma unroll
      for (int f = 0; f < 2; f++) {
        f32x4 t0 = tileT<USEWS, 4, 2>(WF, A.l2w2, 64, OFF_L2W2, b1, bias, 128, 2 * f, l, c, u);
        f32x4 t1 = tileT<USEWS, 4, 2>(WF, A.l2w2, 64, OFF_L2W2, b1, bias, 128, 2 * f + 1, l, c, u);
        b2[f] = pack2<1>(t0, t1);
      }
      // lin2-L3 (bare) -> key1_j fragments + f32 tiles for the mean
#pragma unroll
      for (int f = 0; f < 2; f++) {
        f32x4 t0 = tileT<USEWS, 4, 2>(WF, A.l2w3, 64, OFF_L2W3, b2, bias, 192, 2 * f, l, c, u);
        f32x4 t1 = tileT<USEWS, 4, 2>(WF, A.l2w3, 64, OFF_L2W3, b2, bias, 192, 2 * f + 1, l, c, u);
        k1f[j][f] = pack2<0>(t0, t1);
        if (j == 0) { msum[2 * f] = t0; msum[2 * f + 1] = t1; }
        else        { msum[2 * f] += t0; msum[2 * f + 1] += t1; }
      }
    }
    // mean -> aM fragments immediately (frees msum before q_jt)
    bf16x8 aM[2];
#pragma unroll
    for (int kc = 0; kc < 2; kc++) {
      f32x4 m0 = 0.5f * msum[2 * kc], m1 = 0.5f * msum[2 * kc + 1];
      aM[kc] = pack2<0>(m0, m1);
    }
    // q_jt: z_j = h_j + 0.5*key1_{1-j}; relu(z@l3)@l4 -> stage in S (k1f dies here)
#pragma unroll
    for (int j = 0; j < 2; j++) {
      const bf16_t* HB = j ? sm.h2b : sm.h1b;
      bf16x8 aZ[2];
#pragma unroll
      for (int kc = 0; kc < 2; kc++) {
        bf16x8 h8 = HG(HB, kc);
        bf16x8 kk = k1f[1 - j][kc];
#pragma unroll
        for (int i = 0; i < 8; i++)
          aZ[kc][i] = (bf16_t)((float)h8[i] + 0.5f * (float)kk[i]);
      }
      bf16x8 bz[2];
#pragma unroll
      for (int f = 0; f < 2; f++) {
        f32x4 t0 = tileT<USEWS, 4, 2>(WF, A.l3w, 64, OFF_L3W, aZ, bias, 512, 2 * f, l, c, u);
        f32x4 t1 = tileT<USEWS, 4, 2>(WF, A.l3w, 64, OFF_L3W, aZ, bias, 512, 2 * f + 1, l, c, u);
        bz[f] = pack2<1>(t0, t1);
      }
#pragma unroll
      for (int nt = 0; nt < 2; nt++) {
        f32x4 tq = tileT<USEWS, 2, 2>(WF, A.l4w, 21, OFF_L4W, bz, bias, 576, nt, l, c, u);
#pragma unroll
        for (int p = 0; p < 4; p++) {
          int n2 = nt * 16 + 4 * u + p;
          if (n2 < 21) S[row * 43 + j * 21 + n2] = tq[p];
        }
      }
    }
    // wave-local writeback (own 16 rows; same-wave DS ordering => no barrier)
    {
      const int ob = qjtBase + (wgbase + rb) * 42;
      const float* Sx = S + rb * 43;
      for (int i2 = l; i2 < 672; i2 += 64)
        out[ob + i2] = Sx[(i2 / 42) * 43 + (i2 % 42)];
    }
    // q_prime chain on aM
    bf16x8 bq[4];
#pragma unroll
    for (int f = 0; f < 4; f++) {
      f32x4 t0 = tileT<USEWS, 8, 2>(WF, A.qpw1, 128, OFF_QP1, aM, bias, 256, 2 * f, l, c, u);
      f32x4 t1 = tileT<USEWS, 8, 2>(WF, A.qpw1, 128, OFF_QP1, aM, bias, 256, 2 * f + 1, l, c, u);
      bq[f] = pack2<2>(t0, t1);
    }
    bf16x8 b3[2];
#pragma unroll
    for (int f = 0; f < 2; f++) {
      f32x4 t0 = tileT<USEWS, 4, 4>(WF, A.qpw2, 64, OFF_QP2, bq, bias, 384, 2 * f, l, c, u);
      f32x4 t1 = tileT<USEWS, 4, 4>(WF, A.qpw2, 64, OFF_QP2, bq, bias, 384, 2 * f + 1, l, c, u);
      b3[f] = pack2<2>(t0, t1);
    }
    float pj = 0.f;
#pragma unroll
    for (int nt = 0; nt < 4; nt++) {
      f32x4 tq = tileT<USEWS, 4, 2>(WF, A.qpw3, 64, OFF_QP3, b3, bias, 448, nt, l, c, u);
      f32x4 w4 = *(const f32x4*)(bias + 672 + nt * 16 + 4 * u);
#pragma unroll
      for (int p = 0; p < 4; p++) pj += eluf(tq[p]) * w4[p];
    }
    pj += __shfl_xor(pj, 16, 64);
    pj += __shfl_xor(pj, 32, 64);
    if (u == 0) out[jointBase + wgbase + row] = pj + bias[737];
  };

  J(sm.acts, O_JQ, O_QJT);
  J(sm.amax, O_JMQ, O_QJTM);
}

extern "C" void kernel_launch(void* const* d_in, const int* in_sizes, int n_in,
                              void* d_out, int out_size, void* d_ws, size_t ws_size,
                              hipStream_t stream) {
  (void)in_sizes; (void)n_in; (void)out_size;
  Args A;
  A.x    = (const float*)d_in[0];
  A.a1   = (const int*)d_in[1];
  A.a2   = (const int*)d_in[2];
  A.ew1  = (const float*)d_in[3];
  A.eb1  = (const float*)d_in[4];
  A.ew2  = (const float*)d_in[5];
  A.eb2  = (const float*)d_in[6];
  A.qw1  = (const float*)d_in[7];
  A.qb1  = (const float*)d_in[8];
  A.qw2  = (const float*)d_in[9];
  A.qb2  = (const float*)d_in[10];
  A.vw1  = (const float*)d_in[11];
  A.vb1  = (const float*)d_in[12];
  A.vw2  = (const float*)d_in[13];
  A.vb2  = (const float*)d_in[14];
  A.l2w1 = (const float*)d_in[15];
  A.l2b1 = (const float*)d_in[16];
  A.l2w2 = (const float*)d_in[17];
  A.l2b2 = (const float*)d_in[18];
  A.l2w3 = (const float*)d_in[19];
  A.l2b3 = (const float*)d_in[20];
  A.l3w  = (const float*)d_in[21];
  A.l3b  = (const float*)d_in[22];
  A.l4w  = (const float*)d_in[23];
  A.l4b  = (const float*)d_in[24];
  A.qpw1 = (const float*)d_in[25];
  A.qpb1 = (const float*)d_in[26];
  A.qpw2 = (const float*)d_in[27];
  A.qpb2 = (const float*)d_in[28];
  A.qpw3 = (const float*)d_in[29];
  A.qpb3 = (const float*)d_in[30];
  A.qpw4 = (const float*)d_in[31];
  A.qpb4 = (const float*)d_in[32];
  A.out  = (float*)d_out;
  A.ws   = (const bf16_t*)d_ws;

  if (ws_size >= (size_t)WS_BYTES) {
    bf16_t* ws = (bf16_t*)d_ws;
    RPack P;
    P.d[0] = {A.vw1,  64, 64,  4, OFF_VW1};
    P.d[1] = {A.l2w1, 64, 64,  4, OFF_L2W1};   // rows 0..63 (one-hot rows from global)
    P.d[2] = {A.l2w2, 64, 64,  4, OFF_L2W2};
    P.d[3] = {A.l2w3, 64, 64,  4, OFF_L2W3};
    P.d[4] = {A.l3w,  64, 64,  4, OFF_L3W};
    P.d[5] = {A.l4w,  64, 21,  2, OFF_L4W};    // N padded 21 -> 32 with zeros
    P.d[6] = {A.qpw1, 64, 128, 8, OFF_QP1};
    P.d[7] = {A.qpw2, 128, 64, 4, OFF_QP2};
    P.d[8] = {A.qpw3, 64, 64,  4, OFF_QP3};
    hipLaunchKernelGGL(repack_kernel, dim3(9), dim3(256), 0, stream, P, ws);
    hipLaunchKernelGGL(HIP_KERNEL_NAME(qtran_main<true>), dim3(B_TOT / 64), dim3(256), 0,
                       stream, A);
  } else {
    hipLaunchKernelGGL(HIP_KERNEL_NAME(qtran_main<false>), dim3(B_TOT / 64), dim3(256), 0,
                       stream, A);
  }
}